// Round 6
// baseline (472.765 us; speedup 1.0000x reference)
//
#include <hip/hip_runtime.h>
#include <hip/hip_bf16.h>

// Problem constants
#define BB 8
#define TT 2048
#define DD 1024   // d_model
#define FF 1024   // ff dim

typedef __attribute__((ext_vector_type(8))) short bf16x8;
typedef __attribute__((ext_vector_type(4))) float f32x4;
typedef __attribute__((ext_vector_type(4))) short s16x4;

constexpr float kScaleLog2e = 0.03125f * 1.44269504088896340736f;

__device__ __forceinline__ short bf16_bits(float x) {
    __hip_bfloat16 h = __float2bfloat16(x);
    short s;
    __builtin_memcpy(&s, &h, sizeof(short));
    return s;
}

// ---------------------------------------------------------------------------
// wv2[d] = sum_f Wk[f][d] * bq[f]   (f32).  Grid 4 x 256.
// ---------------------------------------------------------------------------
__global__ __launch_bounds__(256) void wv2k(
    const float* __restrict__ Wk, const float* __restrict__ bq,
    float* __restrict__ wv2)
{
    const int d = blockIdx.x * 256 + threadIdx.x;
    float acc = 0.f;
#pragma unroll 8
    for (int f = 0; f < 1024; ++f) acc += Wk[(size_t)f * 1024 + d] * bq[f];
    wv2[d] = acc;
}

// ---------------------------------------------------------------------------
// cvt_all: seq->Xbuf bf16 + w[row]=seq_row.wv2 (8192 blocks, 2 rows each);
// Wv->Wvb bf16 (512); Wq->WqT bf16 transpose (256); Wk->WkT (256).
// ---------------------------------------------------------------------------
__global__ __launch_bounds__(256) void cvt_all(
    const float* __restrict__ seq, const float* __restrict__ Wq,
    const float* __restrict__ Wk, const float* __restrict__ Wv,
    const float* __restrict__ wv2,
    short* __restrict__ Xbuf, short* __restrict__ Wvb,
    short* __restrict__ WqT, short* __restrict__ WkT,
    float* __restrict__ w)
{
    __shared__ float red[256];
    __shared__ short ldt[64 * 66];
    const int bid = blockIdx.x;
    const int tid = threadIdx.x;

    if (bid < 8192) {
        // 2 rows of seq -> bf16 + dot with wv2
        const int i = bid * 256 + tid;                 // bf16x8 index
        f32x4 a = ((const f32x4*)seq)[2 * i];
        f32x4 b = ((const f32x4*)seq)[2 * i + 1];
        bf16x8 o;
        const int col0 = (tid & 127) * 8;
        float part = 0.f;
#pragma unroll
        for (int j = 0; j < 4; ++j) {
            o[j] = bf16_bits(a[j]);     part += a[j] * wv2[col0 + j];
            o[4 + j] = bf16_bits(b[j]); part += b[j] * wv2[col0 + 4 + j];
        }
        ((bf16x8*)Xbuf)[i] = o;
        red[tid] = part;
        __syncthreads();
#pragma unroll
        for (int s = 64; s >= 1; s >>= 1) {
            if ((tid & 127) < s) red[tid] += red[tid + s];
            __syncthreads();
        }
        if (tid == 0)   w[bid * 2]     = red[0];
        if (tid == 128) w[bid * 2 + 1] = red[128];
        return;
    }
    if (bid < 8704) {
        // Wv -> Wvb (plain bf16)
        const int i = (bid - 8192) * 256 + tid;
        f32x4 a = ((const f32x4*)Wv)[2 * i];
        f32x4 b = ((const f32x4*)Wv)[2 * i + 1];
        bf16x8 o;
#pragma unroll
        for (int j = 0; j < 4; ++j) { o[j] = bf16_bits(a[j]); o[4 + j] = bf16_bits(b[j]); }
        ((bf16x8*)Wvb)[i] = o;
        return;
    }
    // transpose: Wq (256 tiles) or Wk (256 tiles), 64x64 per block
    const float* src = (bid < 8960) ? Wq : Wk;
    short* dst       = (bid < 8960) ? WqT : WkT;
    const int tt = (bid < 8960) ? (bid - 8704) : (bid - 8960);
    const int tr = tt >> 4, tc = tt & 15;         // f-tile, d-tile
    {
        const int fr = tid >> 2, dg = tid & 3;
        const float* s0 = src + (size_t)(tr * 64 + fr) * 1024 + tc * 64 + dg * 16;
#pragma unroll
        for (int q = 0; q < 4; ++q) {
            f32x4 a = ((const f32x4*)s0)[q];
#pragma unroll
            for (int j = 0; j < 4; ++j)
                ldt[(dg * 16 + q * 4 + j) * 66 + fr] = bf16_bits(a[j]);
        }
    }
    __syncthreads();
    {
        const int dr = tid >> 2, fg = tid & 3;
        bf16x8 o0, o1;
#pragma unroll
        for (int j = 0; j < 8; ++j) {
            o0[j] = ldt[dr * 66 + fg * 16 + j];
            o1[j] = ldt[dr * 66 + fg * 16 + 8 + j];
        }
        short* d0 = dst + (size_t)(tc * 64 + dr) * 1024 + tr * 64 + fg * 16;
        *(bf16x8*)d0 = o0;
        *(bf16x8*)(d0 + 8) = o1;
    }
}

// ===========================================================================
// 256x256 bf16 GEMM core (round-2 exact: best measured, 127 us qkv).
// 4 compute phases per K-tile (BK=64), 2 s_barrier/K-tile, counted vmcnt.
// Ring of 4 K-half slots per operand; swizzle chunk cp = kg ^ ((row>>1)&3).
// ===========================================================================
#define SLOT 8192   // shorts per K-half slot (256 rows x 32 k)

__device__ __forceinline__ void stage2(const short* g0, const short* g1,
                                       short* slot, int lo0, int lo1) {
    __builtin_amdgcn_global_load_lds(
        (const __attribute__((address_space(1))) unsigned int*)g0,
        (__attribute__((address_space(3))) unsigned int*)(slot + lo0), 16, 0, 0);
    __builtin_amdgcn_global_load_lds(
        (const __attribute__((address_space(1))) unsigned int*)g1,
        (__attribute__((address_space(3))) unsigned int*)(slot + lo1), 16, 0, 0);
}

template<int W>
__device__ __forceinline__ void tile_barrier() {
    if constexpr (W == 8)      asm volatile("s_waitcnt vmcnt(8)" ::: "memory");
    else if constexpr (W == 4) asm volatile("s_waitcnt vmcnt(4)" ::: "memory");
    else if constexpr (W == 0) asm volatile("s_waitcnt vmcnt(0)" ::: "memory");
    __builtin_amdgcn_s_barrier();
    __builtin_amdgcn_sched_barrier(0);
}

__device__ __forceinline__ void lgkm_gate() {
    asm volatile("s_waitcnt lgkmcnt(0)" ::: "memory");
    __builtin_amdgcn_sched_barrier(0);
}

template<bool S12, bool S34, int WMID, int WEND>
__device__ __forceinline__ void tile_body(
    int t, short* As, short* Bs,
    const short* a0, const short* a1, const short* b0, const short* b1,
    int lo0, int lo1, int wm, int wn, int rk, f32x4 (&acc)[8][4])
{
    const short* sA0 = As + ((2 * t) & 3) * SLOT;
    const short* sB0 = Bs + ((2 * t) & 3) * SLOT;
    const short* sA1 = As + ((2 * t + 1) & 3) * SLOT;
    const short* sB1 = Bs + ((2 * t + 1) & 3) * SLOT;

    bf16x8 a[4], b[4];

    // P1
#pragma unroll
    for (int m = 0; m < 4; ++m) a[m] = *(const bf16x8*)(sA0 + (wm + m * 16) * 32 + rk);
#pragma unroll
    for (int n = 0; n < 4; ++n) b[n] = *(const bf16x8*)(sB0 + (wn + n * 16) * 32 + rk);
    if constexpr (S12)
        stage2(a0 + (2 * t + 3) * 32, a1 + (2 * t + 3) * 32,
               As + ((2 * t + 3) & 3) * SLOT, lo0, lo1);
    lgkm_gate();
    __builtin_amdgcn_s_setprio(1);
#pragma unroll
    for (int m = 0; m < 4; ++m)
#pragma unroll
        for (int n = 0; n < 4; ++n)
            acc[m][n] = __builtin_amdgcn_mfma_f32_16x16x32_bf16(a[m], b[n], acc[m][n], 0, 0, 0);
    __builtin_amdgcn_s_setprio(0);

    // P2
#pragma unroll
    for (int m = 0; m < 4; ++m) a[m] = *(const bf16x8*)(sA0 + (wm + 64 + m * 16) * 32 + rk);
    if constexpr (S12)
        stage2(b0 + (2 * t + 3) * 32, b1 + (2 * t + 3) * 32,
               Bs + ((2 * t + 3) & 3) * SLOT, lo0, lo1);
    lgkm_gate();
    __builtin_amdgcn_s_setprio(1);
#pragma unroll
    for (int m = 0; m < 4; ++m)
#pragma unroll
        for (int n = 0; n < 4; ++n)
            acc[m + 4][n] = __builtin_amdgcn_mfma_f32_16x16x32_bf16(a[m], b[n], acc[m + 4][n], 0, 0, 0);
    __builtin_amdgcn_s_setprio(0);

    tile_barrier<WMID>();

    // P3
#pragma unroll
    for (int m = 0; m < 4; ++m) a[m] = *(const bf16x8*)(sA1 + (wm + m * 16) * 32 + rk);
#pragma unroll
    for (int n = 0; n < 4; ++n) b[n] = *(const bf16x8*)(sB1 + (wn + n * 16) * 32 + rk);
    if constexpr (S34)
        stage2(a0 + (2 * t + 4) * 32, a1 + (2 * t + 4) * 32,
               As + ((2 * t + 4) & 3) * SLOT, lo0, lo1);
    lgkm_gate();
    __builtin_amdgcn_s_setprio(1);
#pragma unroll
    for (int m = 0; m < 4; ++m)
#pragma unroll
        for (int n = 0; n < 4; ++n)
            acc[m][n] = __builtin_amdgcn_mfma_f32_16x16x32_bf16(a[m], b[n], acc[m][n], 0, 0, 0);
    __builtin_amdgcn_s_setprio(0);

    // P4
#pragma unroll
    for (int m = 0; m < 4; ++m) a[m] = *(const bf16x8*)(sA1 + (wm + 64 + m * 16) * 32 + rk);
    if constexpr (S34)
        stage2(b0 + (2 * t + 4) * 32, b1 + (2 * t + 4) * 32,
               Bs + ((2 * t + 4) & 3) * SLOT, lo0, lo1);
    lgkm_gate();
    __builtin_amdgcn_s_setprio(1);
#pragma unroll
    for (int m = 0; m < 4; ++m)
#pragma unroll
        for (int n = 0; n < 4; ++n)
            acc[m + 4][n] = __builtin_amdgcn_mfma_f32_16x16x32_bf16(a[m], b[n], acc[m + 4][n], 0, 0, 0);
    __builtin_amdgcn_s_setprio(0);

    if constexpr (WEND >= 0)
        tile_barrier<WEND>();
}

__device__ __forceinline__ void gemm256(
    const short* __restrict__ A, int lda, int m0,
    const short* __restrict__ B, int ldb, int n0,
    int T, short* As, short* Bs, f32x4 (&acc)[8][4])
{
    const int tid  = threadIdx.x;
    const int lane = tid & 63;
    const int w    = tid >> 6;
    const int wm   = (w >> 2) * 128;
    const int wn   = (w & 3) * 64;
    const int r    = lane & 15;
    const int qd   = lane >> 4;
    const int rk   = r * 32 + (qd ^ ((r >> 1) & 3)) * 8;

    const int s0   = w * 128 + lane, s1 = s0 + 64;
    const int row0 = s0 >> 2,  row1 = s1 >> 2;
    const int cl0  = (s0 & 3) ^ ((row0 >> 1) & 3);
    const int cl1  = (s1 & 3) ^ ((row1 >> 1) & 3);
    const short* a0 = A + (size_t)(m0 + row0) * lda + cl0 * 8;
    const short* a1 = A + (size_t)(m0 + row1) * lda + cl1 * 8;
    const short* b0 = B + (size_t)(n0 + row0) * ldb + cl0 * 8;
    const short* b1 = B + (size_t)(n0 + row1) * ldb + cl1 * 8;
    const int lo0 = s0 * 8, lo1 = s1 * 8;

    stage2(a0,      a1,      As,            lo0, lo1);
    stage2(b0,      b1,      Bs,            lo0, lo1);
    stage2(a0 + 32, a1 + 32, As + SLOT,     lo0, lo1);
    stage2(b0 + 32, b1 + 32, Bs + SLOT,     lo0, lo1);
    stage2(a0 + 64, a1 + 64, As + 2 * SLOT, lo0, lo1);
    stage2(b0 + 64, b1 + 64, Bs + 2 * SLOT, lo0, lo1);
    tile_barrier<8>();

    for (int t = 0; t < T - 2; ++t)
        tile_body<true, true, 8, 8>(t, As, Bs, a0, a1, b0, b1, lo0, lo1, wm, wn, rk, acc);
    tile_body<true,  false, 8, 4>(T - 2, As, Bs, a0, a1, b0, b1, lo0, lo1, wm, wn, rk, acc);
    tile_body<false, false, 0, -1>(T - 1, As, Bs, a0, a1, b0, b1, lo0, lo1, wm, wn, rk, acc);
}

// ---------------------------------------------------------------------------
// W2 split-K: partial[slice][g][d] = sum_{f in slice*128..+128} WkT[g][f]WqT[d][f]
// Grid 128 = 16 (4x4 of 256^2) x 8 slices; T=2 K-tiles.
// ---------------------------------------------------------------------------
__global__ __launch_bounds__(512, 2) void w2split(
    const short* __restrict__ WkT, const short* __restrict__ WqT,
    float* __restrict__ Wpart)
{
    __shared__ short As[4 * SLOT], Bs[4 * SLOT];
    const int gt = blockIdx.x >> 3, slice = blockIdx.x & 7;
    const int gm = gt >> 2, gn = gt & 3;

    f32x4 acc[8][4];
#pragma unroll
    for (int m = 0; m < 8; ++m)
#pragma unroll
        for (int n = 0; n < 4; ++n) acc[m][n] = (f32x4){0.f, 0.f, 0.f, 0.f};

    gemm256(WkT + slice * 128, 1024, gm * 256,
            WqT + slice * 128, 1024, gn * 256, 2, As, Bs, acc);

    const int lane = threadIdx.x & 63;
    const int w    = threadIdx.x >> 6;
    const int wm   = (w >> 2) * 128;
    const int wn   = (w & 3) * 64;
    const int r    = lane & 15;
    const int qd   = lane >> 4;
    const int row_base = gm * 256 + wm + qd * 4;
    const int col_base = gn * 256 + wn + r;
    float* dst = Wpart + (size_t)slice * 1048576;
#pragma unroll
    for (int mf = 0; mf < 8; ++mf)
#pragma unroll
        for (int nf = 0; nf < 4; ++nf)
#pragma unroll
            for (int i = 0; i < 4; ++i)
                dst[(size_t)(row_base + mf * 16 + i) * 1024 + col_base + nf * 16] = acc[mf][nf][i];
}

// ---------------------------------------------------------------------------
// W2 reduce: W2Tb[g][d] = bf16(sum_slices).  Grid 1024 x 256, 4 elems/thread.
// ---------------------------------------------------------------------------
__global__ __launch_bounds__(256) void w2red(
    const float* __restrict__ Wpart, short* __restrict__ W2Tb)
{
    const int base = blockIdx.x * 1024 + threadIdx.x * 4;
    f32x4 s = (f32x4){0.f, 0.f, 0.f, 0.f};
#pragma unroll
    for (int sl = 0; sl < 8; ++sl) {
        f32x4 p = *(const f32x4*)(Wpart + (size_t)sl * 1048576 + base);
#pragma unroll
        for (int j = 0; j < 4; ++j) s[j] += p[j];
    }
    s16x4 o;
#pragma unroll
    for (int j = 0; j < 4; ++j) o[j] = bf16_bits(s[j]);
    *(s16x4*)(W2Tb + base) = o;
}

// ---------------------------------------------------------------------------
// proj: p0: Ybuf = Xbuf @ W2Tb^T (no bias); p1: vT = transpose(Xbuf @ Wvb^T + bv).
// Grid 512 = 64 mt x 4 nt x 2 p, XCD-chunked.
// ---------------------------------------------------------------------------
__global__ __launch_bounds__(512, 2) void proj(
    const short* __restrict__ Xbuf, const short* __restrict__ W2Tb,
    const short* __restrict__ Wvb, const float* __restrict__ bv,
    __hip_bfloat16* __restrict__ Ybuf, __hip_bfloat16* __restrict__ vT)
{
    __shared__ short As[4 * SLOT], Bs[4 * SLOT];
    const int bid  = blockIdx.x;
    const int id2  = (bid & 7) * 64 + (bid >> 3);   // bijective (512 % 8 == 0)
    const int mt   = id2 >> 3;
    const int rest = id2 & 7;
    const int nt   = rest & 3;
    const int p    = rest >> 2;

    const short* W = (p == 0) ? W2Tb : Wvb;

    f32x4 acc[8][4];
#pragma unroll
    for (int m = 0; m < 8; ++m)
#pragma unroll
        for (int n = 0; n < 4; ++n) acc[m][n] = (f32x4){0.f, 0.f, 0.f, 0.f};

    gemm256(Xbuf, DD, mt * 256, W, DD, nt * 256, DD / 64, As, Bs, acc);

    const int lane = threadIdx.x & 63;
    const int w    = threadIdx.x >> 6;
    const int wm   = (w >> 2) * 128;
    const int wn   = (w & 3) * 64;
    const int r    = lane & 15;
    const int qd   = lane >> 4;
    const int row_base = mt * 256 + wm + qd * 4;
    const int col_base = nt * 256 + wn + r;

    if (p == 0) {
#pragma unroll
        for (int nf = 0; nf < 4; ++nf) {
            const int col = col_base + nf * 16;
#pragma unroll
            for (int mf = 0; mf < 8; ++mf)
#pragma unroll
                for (int i = 0; i < 4; ++i)
                    Ybuf[(size_t)(row_base + mf * 16 + i) * FF + col] =
                        __float2bfloat16(acc[mf][nf][i]);
        }
    } else {
        // transposed V: lane's 4 regs = 4 consecutive t -> 8B packed store
#pragma unroll
        for (int mf = 0; mf < 8; ++mf) {
            const int rowg = row_base + mf * 16;
            const int b_   = rowg >> 11;
            const int t_   = rowg & 2047;
            __hip_bfloat16* vb = vT + (size_t)b_ * FF * TT;
#pragma unroll
            for (int nf = 0; nf < 4; ++nf) {
                const int col = col_base + nf * 16;
                const float bvv = bv[col];
                s16x4 pack;
#pragma unroll
                for (int i = 0; i < 4; ++i) pack[i] = bf16_bits(acc[mf][nf][i] + bvv);
                *(s16x4*)(vb + (size_t)col * TT + t_) = pack;
            }
        }
    }
}

// ---------------------------------------------------------------------------
// score: P[b][t][s] = exp2((y.x + w[s]) * scale*log2e) bf16, Z += rowsum.
// Grid 512 = 8 b x 8 tt x 8 st; XCD-chunked (one b per XCD).
// ---------------------------------------------------------------------------
__global__ __launch_bounds__(512, 2) void score256(
    const __hip_bfloat16* __restrict__ Ybuf, const short* __restrict__ Xbuf,
    const float* __restrict__ w, __hip_bfloat16* __restrict__ P,
    float* __restrict__ Z)
{
    __shared__ short As[4 * SLOT], Bs[4 * SLOT];
    const int bid = blockIdx.x;
    const int id2 = (bid & 7) * 64 + (bid >> 3);
    const int b   = id2 >> 6;
    const int tt  = (id2 >> 3) & 7;
    const int st  = id2 & 7;

    const short* yb = (const short*)Ybuf + (size_t)b * TT * FF;
    const short* xb = Xbuf + (size_t)b * TT * FF;

    f32x4 acc[8][4];
#pragma unroll
    for (int m = 0; m < 8; ++m)
#pragma unroll
        for (int n = 0; n < 4; ++n) acc[m][n] = (f32x4){0.f, 0.f, 0.f, 0.f};

    gemm256(yb, FF, tt * 256, xb, FF, st * 256, FF / 64, As, Bs, acc);

    const int lane = threadIdx.x & 63;
    const int wv   = threadIdx.x >> 6;
    const int wm   = (wv >> 2) * 128;
    const int wn   = (wv & 3) * 64;
    const int r    = lane & 15;
    const int qd   = lane >> 4;
    const int row_base = tt * 256 + wm + qd * 4;
    const int col_base = st * 256 + wn + r;

    __hip_bfloat16* Pb = P + (size_t)b * TT * TT;
    float* Zb = Z + b * TT;
    const float* wb = w + (size_t)b * TT;

    float rs[8][4];
#pragma unroll
    for (int mf = 0; mf < 8; ++mf)
#pragma unroll
        for (int i = 0; i < 4; ++i) rs[mf][i] = 0.f;

#pragma unroll
    for (int nf = 0; nf < 4; ++nf) {
        const int col = col_base + nf * 16;
        const float ws_ = wb[col];
#pragma unroll
        for (int mf = 0; mf < 8; ++mf)
#pragma unroll
            for (int i = 0; i < 4; ++i) {
                const float e = exp2f((acc[mf][nf][i] + ws_) * kScaleLog2e);
                const __hip_bfloat16 eb = __float2bfloat16(e);
                rs[mf][i] += __bfloat162float(eb);
                Pb[(size_t)(row_base + mf * 16 + i) * TT + col] = eb;
            }
    }
#pragma unroll
    for (int off = 1; off < 16; off <<= 1)
#pragma unroll
        for (int mf = 0; mf < 8; ++mf)
#pragma unroll
            for (int i = 0; i < 4; ++i) rs[mf][i] += __shfl_xor(rs[mf][i], off, 64);
    if (r == 0) {
#pragma unroll
        for (int mf = 0; mf < 8; ++mf)
#pragma unroll
            for (int i = 0; i < 4; ++i)
                atomicAdd(&Zb[row_base + mf * 16 + i], rs[mf][i]);
    }
}

// ---------------------------------------------------------------------------
// pv: out[b][t][f] = (P @ V)/Z via vT.  Grid 256 = 8 b x 8 tt x 4 ft.
// ---------------------------------------------------------------------------
__global__ __launch_bounds__(512, 2) void pv256(
    const __hip_bfloat16* __restrict__ P, const __hip_bfloat16* __restrict__ vT,
    const float* __restrict__ Z, float* __restrict__ out)
{
    __shared__ short As[4 * SLOT], Bs[4 * SLOT];
    const int bid = blockIdx.x;
    const int id2 = (bid & 7) * 32 + (bid >> 3);
    const int b   = id2 >> 5;
    const int tt  = (id2 >> 2) & 7;
    const int ft  = id2 & 3;

    const short* Pb = (const short*)P + (size_t)b * TT * TT;
    const short* vb = (const short*)vT + (size_t)b * FF * TT;

    f32x4 acc[8][4];
#pragma unroll
    for (int m = 0; m < 8; ++m)
#pragma unroll
        for (int n = 0; n < 4; ++n) acc[m][n] = (f32x4){0.f, 0.f, 0.f, 0.f};

    gemm256(Pb, TT, tt * 256, vb, TT, ft * 256, TT / 64, As, Bs, acc);

    const int lane = threadIdx.x & 63;
    const int w    = threadIdx.x >> 6;
    const int wm   = (w >> 2) * 128;
    const int wn   = (w & 3) * 64;
    const int r    = lane & 15;
    const int qd   = lane >> 4;
    const int row_base = tt * 256 + wm + qd * 4;
    const int col_base = ft * 256 + wn + r;

    const float* Zb = Z + b * TT;
    float* ob = out + (size_t)b * TT * FF;

#pragma unroll
    for (int mf = 0; mf < 8; ++mf) {
        float rz[4];
#pragma unroll
        for (int i = 0; i < 4; ++i) rz[i] = 1.0f / Zb[row_base + mf * 16 + i];
#pragma unroll
        for (int nf = 0; nf < 4; ++nf) {
            const int col = col_base + nf * 16;
#pragma unroll
            for (int i = 0; i < 4; ++i)
                ob[(size_t)(row_base + mf * 16 + i) * FF + col] = acc[mf][nf][i] * rz[i];
        }
    }
}

// ---------------------------------------------------------------------------
extern "C" void kernel_launch(void* const* d_in, const int* in_sizes, int n_in,
                              void* d_out, int out_size, void* d_ws, size_t ws_size,
                              hipStream_t stream) {
    const float* seq = (const float*)d_in[0];
    const float* Wq  = (const float*)d_in[1];
    const float* bq  = (const float*)d_in[2];
    const float* Wk  = (const float*)d_in[3];
    const float* bk  = (const float*)d_in[4];  (void)bk;  // cancels in softmax
    const float* Wv  = (const float*)d_in[5];
    const float* bv  = (const float*)d_in[6];
    float* out = (float*)d_out;
    char* ws = (char*)d_ws;

    // Workspace (167,837,696 B):
    //   Xbuf : 32 MiB @ 0          (bf16 x; score B-operand; persists)
    //   Ybuf : 32 MiB @ 32M        (bf16 y = x.W2)
    //   vT   : 32 MiB @ 64M
    //   P    : 64 MiB @ 96M        (pre-score aliases: WqT@+0 2M, WkT@+2M,
    //                               Wvb@+4M, W2Tb@+6M, Wpart@+8M 32M f32)
    //   Z    : 64 KiB @ 160M       (wv2 4 KiB aliases Z pre-memset)
    //   w    : 64 KiB in d_out[0..64K) (dead before pv overwrites out)
    const size_t MB32 = 33554432;
    short* Xbuf = (short*)(ws);
    __hip_bfloat16* Ybuf = (__hip_bfloat16*)(ws + MB32);
    __hip_bfloat16* vT   = (__hip_bfloat16*)(ws + 2 * MB32);
    char*  Pr   = ws + 3 * MB32;
    __hip_bfloat16* P = (__hip_bfloat16*)Pr;
    short* WqT  = (short*)(Pr);
    short* WkT  = (short*)(Pr + 2097152);
    short* Wvb  = (short*)(Pr + 4194304);
    short* W2Tb = (short*)(Pr + 6291456);
    float* Wpart= (float*)(Pr + 8388608);
    float* Z    = (float*)(ws + 3 * MB32 + (size_t)67108864);
    float* wv2  = Z;                         // alias, dead before memset
    float* w    = (float*)d_out;             // dead before pv writes out

    wv2k<<<4, 256, 0, stream>>>(Wk, bq, wv2);
    cvt_all<<<9216, 256, 0, stream>>>(seq, Wq, Wk, Wv, wv2, Xbuf, Wvb, WqT, WkT, w);
    w2split<<<128, 512, 0, stream>>>(WkT, WqT, Wpart);
    w2red<<<1024, 256, 0, stream>>>(Wpart, W2Tb);
    proj<<<512, 512, 0, stream>>>(Xbuf, W2Tb, Wvb, bv, Ybuf, vT);
    hipMemsetAsync(Z, 0, (size_t)BB * TT * sizeof(float), stream);
    score256<<<BB * 64, 512, 0, stream>>>(Ybuf, Xbuf, w, P, Z);
    pv256<<<BB * 32, 512, 0, stream>>>(P, vT, Z, out);
}

// Round 7
// 405.235 us; speedup vs baseline: 1.1666x; 1.1666x over previous
//
#include <hip/hip_runtime.h>
#include <hip/hip_bf16.h>

// Problem constants
#define BB 8
#define TT 2048
#define DD 1024   // d_model
#define FF 1024   // ff dim

typedef __attribute__((ext_vector_type(8))) short bf16x8;
typedef __attribute__((ext_vector_type(4))) float f32x4;
typedef __attribute__((ext_vector_type(4))) short s16x4;

constexpr float kScaleLog2e = 0.03125f * 1.44269504088896340736f;

__device__ __forceinline__ short bf16_bits(float x) {
    __hip_bfloat16 h = __float2bfloat16(x);
    short s;
    __builtin_memcpy(&s, &h, sizeof(short));
    return s;
}

__device__ __forceinline__ float bf16_val(short s) {
    __hip_bfloat16 h;
    __builtin_memcpy(&h, &s, sizeof(short));
    return __bfloat162float(h);
}

// ---------------------------------------------------------------------------
// cvt_all: seq->Xbuf bf16 (8192 blocks, pure convert — r6's serial w-reduce
// removed); Wv->Wvb bf16 (512); Wq->WqT bf16 transpose (256); Wk->WkT (256).
// ---------------------------------------------------------------------------
__global__ __launch_bounds__(256) void cvt_all(
    const float* __restrict__ seq, const float* __restrict__ Wq,
    const float* __restrict__ Wk, const float* __restrict__ Wv,
    short* __restrict__ Xbuf, short* __restrict__ Wvb,
    short* __restrict__ WqT, short* __restrict__ WkT)
{
    __shared__ short ldt[64 * 66];
    const int bid = blockIdx.x;
    const int tid = threadIdx.x;

    if (bid < 8192) {
        const int i = bid * 256 + tid;                 // bf16x8 index
        f32x4 a = ((const f32x4*)seq)[2 * i];
        f32x4 b = ((const f32x4*)seq)[2 * i + 1];
        bf16x8 o;
#pragma unroll
        for (int j = 0; j < 4; ++j) { o[j] = bf16_bits(a[j]); o[4 + j] = bf16_bits(b[j]); }
        ((bf16x8*)Xbuf)[i] = o;
        return;
    }
    if (bid < 8704) {
        const int i = (bid - 8192) * 256 + tid;
        f32x4 a = ((const f32x4*)Wv)[2 * i];
        f32x4 b = ((const f32x4*)Wv)[2 * i + 1];
        bf16x8 o;
#pragma unroll
        for (int j = 0; j < 4; ++j) { o[j] = bf16_bits(a[j]); o[4 + j] = bf16_bits(b[j]); }
        ((bf16x8*)Wvb)[i] = o;
        return;
    }
    // transpose: Wq (256 tiles) or Wk (256 tiles), 64x64 per block
    const float* src = (bid < 8960) ? Wq : Wk;
    short* dst       = (bid < 8960) ? WqT : WkT;
    const int tt = (bid < 8960) ? (bid - 8704) : (bid - 8960);
    const int tr = tt >> 4, tc = tt & 15;         // f-tile, d-tile
    {
        const int fr = tid >> 2, dg = tid & 3;
        const float* s0 = src + (size_t)(tr * 64 + fr) * 1024 + tc * 64 + dg * 16;
#pragma unroll
        for (int q = 0; q < 4; ++q) {
            f32x4 a = ((const f32x4*)s0)[q];
#pragma unroll
            for (int j = 0; j < 4; ++j)
                ldt[(dg * 16 + q * 4 + j) * 66 + fr] = bf16_bits(a[j]);
        }
    }
    __syncthreads();
    {
        const int dr = tid >> 2, fg = tid & 3;
        bf16x8 o0, o1;
#pragma unroll
        for (int j = 0; j < 8; ++j) {
            o0[j] = ldt[dr * 66 + fg * 16 + j];
            o1[j] = ldt[dr * 66 + fg * 16 + 8 + j];
        }
        short* d0 = dst + (size_t)(tc * 64 + dr) * 1024 + tr * 64 + fg * 16;
        *(bf16x8*)d0 = o0;
        *(bf16x8*)(d0 + 8) = o1;
    }
}

// ---------------------------------------------------------------------------
// wv2[d] = dot(WkT[d][:], bq)  — wave per d-row, coalesced 2 KB/row.
// Grid 256 x 256 (4 waves/block).  Replaces r6's 4-block latency-bound wv2k.
// ---------------------------------------------------------------------------
__global__ __launch_bounds__(256) void wv2k2(
    const short* __restrict__ WkT, const float* __restrict__ bq,
    float* __restrict__ wv2)
{
    const int wv   = threadIdx.x >> 6;
    const int lane = threadIdx.x & 63;
    const int d    = blockIdx.x * 4 + wv;
    const short* row = WkT + (size_t)d * 1024 + lane * 16;
    bf16x8 x0 = *(const bf16x8*)row;
    bf16x8 x1 = *(const bf16x8*)(row + 8);
    const float* bl = bq + lane * 16;
    float s = 0.f;
#pragma unroll
    for (int j = 0; j < 8; ++j) s += bf16_val(x0[j]) * bl[j];
#pragma unroll
    for (int j = 0; j < 8; ++j) s += bf16_val(x1[j]) * bl[8 + j];
#pragma unroll
    for (int off = 1; off < 64; off <<= 1) s += __shfl_xor(s, off, 64);
    if (lane == 0) wv2[d] = s;
}

// ---------------------------------------------------------------------------
// w[row] = dot(Xbuf[row][:], wv2)  — wave per row.  Grid 4096 x 256.
// wv2 (4 KB) is L2-hot after first touch.
// ---------------------------------------------------------------------------
__global__ __launch_bounds__(256) void wrow(
    const short* __restrict__ Xbuf, const float* __restrict__ wv2,
    float* __restrict__ w)
{
    const int wv   = threadIdx.x >> 6;
    const int lane = threadIdx.x & 63;
    const int row  = blockIdx.x * 4 + wv;
    const short* xr = Xbuf + (size_t)row * 1024 + lane * 16;
    bf16x8 x0 = *(const bf16x8*)xr;
    bf16x8 x1 = *(const bf16x8*)(xr + 8);
    const float* vl = wv2 + lane * 16;
    float s = 0.f;
#pragma unroll
    for (int j = 0; j < 8; ++j) s += bf16_val(x0[j]) * vl[j];
#pragma unroll
    for (int j = 0; j < 8; ++j) s += bf16_val(x1[j]) * vl[8 + j];
#pragma unroll
    for (int off = 1; off < 64; off <<= 1) s += __shfl_xor(s, off, 64);
    if (lane == 0) w[row] = s;
}

// ===========================================================================
// 256x256 bf16 GEMM core (round-2 exact: best measured).
// 4 compute phases per K-tile (BK=64), 2 s_barrier/K-tile, counted vmcnt.
// Ring of 4 K-half slots per operand; swizzle chunk cp = kg ^ ((row>>1)&3).
// ===========================================================================
#define SLOT 8192   // shorts per K-half slot (256 rows x 32 k)

__device__ __forceinline__ void stage2(const short* g0, const short* g1,
                                       short* slot, int lo0, int lo1) {
    __builtin_amdgcn_global_load_lds(
        (const __attribute__((address_space(1))) unsigned int*)g0,
        (__attribute__((address_space(3))) unsigned int*)(slot + lo0), 16, 0, 0);
    __builtin_amdgcn_global_load_lds(
        (const __attribute__((address_space(1))) unsigned int*)g1,
        (__attribute__((address_space(3))) unsigned int*)(slot + lo1), 16, 0, 0);
}

template<int W>
__device__ __forceinline__ void tile_barrier() {
    if constexpr (W == 8)      asm volatile("s_waitcnt vmcnt(8)" ::: "memory");
    else if constexpr (W == 4) asm volatile("s_waitcnt vmcnt(4)" ::: "memory");
    else if constexpr (W == 0) asm volatile("s_waitcnt vmcnt(0)" ::: "memory");
    __builtin_amdgcn_s_barrier();
    __builtin_amdgcn_sched_barrier(0);
}

__device__ __forceinline__ void lgkm_gate() {
    asm volatile("s_waitcnt lgkmcnt(0)" ::: "memory");
    __builtin_amdgcn_sched_barrier(0);
}

template<bool S12, bool S34, int WMID, int WEND>
__device__ __forceinline__ void tile_body(
    int t, short* As, short* Bs,
    const short* a0, const short* a1, const short* b0, const short* b1,
    int lo0, int lo1, int wm, int wn, int rk, f32x4 (&acc)[8][4])
{
    const short* sA0 = As + ((2 * t) & 3) * SLOT;
    const short* sB0 = Bs + ((2 * t) & 3) * SLOT;
    const short* sA1 = As + ((2 * t + 1) & 3) * SLOT;
    const short* sB1 = Bs + ((2 * t + 1) & 3) * SLOT;

    bf16x8 a[4], b[4];

    // P1
#pragma unroll
    for (int m = 0; m < 4; ++m) a[m] = *(const bf16x8*)(sA0 + (wm + m * 16) * 32 + rk);
#pragma unroll
    for (int n = 0; n < 4; ++n) b[n] = *(const bf16x8*)(sB0 + (wn + n * 16) * 32 + rk);
    if constexpr (S12)
        stage2(a0 + (2 * t + 3) * 32, a1 + (2 * t + 3) * 32,
               As + ((2 * t + 3) & 3) * SLOT, lo0, lo1);
    lgkm_gate();
    __builtin_amdgcn_s_setprio(1);
#pragma unroll
    for (int m = 0; m < 4; ++m)
#pragma unroll
        for (int n = 0; n < 4; ++n)
            acc[m][n] = __builtin_amdgcn_mfma_f32_16x16x32_bf16(a[m], b[n], acc[m][n], 0, 0, 0);
    __builtin_amdgcn_s_setprio(0);

    // P2
#pragma unroll
    for (int m = 0; m < 4; ++m) a[m] = *(const bf16x8*)(sA0 + (wm + 64 + m * 16) * 32 + rk);
    if constexpr (S12)
        stage2(b0 + (2 * t + 3) * 32, b1 + (2 * t + 3) * 32,
               Bs + ((2 * t + 3) & 3) * SLOT, lo0, lo1);
    lgkm_gate();
    __builtin_amdgcn_s_setprio(1);
#pragma unroll
    for (int m = 0; m < 4; ++m)
#pragma unroll
        for (int n = 0; n < 4; ++n)
            acc[m + 4][n] = __builtin_amdgcn_mfma_f32_16x16x32_bf16(a[m], b[n], acc[m + 4][n], 0, 0, 0);
    __builtin_amdgcn_s_setprio(0);

    tile_barrier<WMID>();

    // P3
#pragma unroll
    for (int m = 0; m < 4; ++m) a[m] = *(const bf16x8*)(sA1 + (wm + m * 16) * 32 + rk);
#pragma unroll
    for (int n = 0; n < 4; ++n) b[n] = *(const bf16x8*)(sB1 + (wn + n * 16) * 32 + rk);
    if constexpr (S34)
        stage2(a0 + (2 * t + 4) * 32, a1 + (2 * t + 4) * 32,
               As + ((2 * t + 4) & 3) * SLOT, lo0, lo1);
    lgkm_gate();
    __builtin_amdgcn_s_setprio(1);
#pragma unroll
    for (int m = 0; m < 4; ++m)
#pragma unroll
        for (int n = 0; n < 4; ++n)
            acc[m][n] = __builtin_amdgcn_mfma_f32_16x16x32_bf16(a[m], b[n], acc[m][n], 0, 0, 0);
    __builtin_amdgcn_s_setprio(0);

    // P4
#pragma unroll
    for (int m = 0; m < 4; ++m) a[m] = *(const bf16x8*)(sA1 + (wm + 64 + m * 16) * 32 + rk);
    if constexpr (S34)
        stage2(b0 + (2 * t + 4) * 32, b1 + (2 * t + 4) * 32,
               Bs + ((2 * t + 4) & 3) * SLOT, lo0, lo1);
    lgkm_gate();
    __builtin_amdgcn_s_setprio(1);
#pragma unroll
    for (int m = 0; m < 4; ++m)
#pragma unroll
        for (int n = 0; n < 4; ++n)
            acc[m + 4][n] = __builtin_amdgcn_mfma_f32_16x16x32_bf16(a[m], b[n], acc[m + 4][n], 0, 0, 0);
    __builtin_amdgcn_s_setprio(0);

    if constexpr (WEND >= 0)
        tile_barrier<WEND>();
}

__device__ __forceinline__ void gemm256(
    const short* __restrict__ A, int lda, int m0,
    const short* __restrict__ B, int ldb, int n0,
    int T, short* As, short* Bs, f32x4 (&acc)[8][4])
{
    const int tid  = threadIdx.x;
    const int lane = tid & 63;
    const int w    = tid >> 6;
    const int wm   = (w >> 2) * 128;
    const int wn   = (w & 3) * 64;
    const int r    = lane & 15;
    const int qd   = lane >> 4;
    const int rk   = r * 32 + (qd ^ ((r >> 1) & 3)) * 8;

    const int s0   = w * 128 + lane, s1 = s0 + 64;
    const int row0 = s0 >> 2,  row1 = s1 >> 2;
    const int cl0  = (s0 & 3) ^ ((row0 >> 1) & 3);
    const int cl1  = (s1 & 3) ^ ((row1 >> 1) & 3);
    const short* a0 = A + (size_t)(m0 + row0) * lda + cl0 * 8;
    const short* a1 = A + (size_t)(m0 + row1) * lda + cl1 * 8;
    const short* b0 = B + (size_t)(n0 + row0) * ldb + cl0 * 8;
    const short* b1 = B + (size_t)(n0 + row1) * ldb + cl1 * 8;
    const int lo0 = s0 * 8, lo1 = s1 * 8;

    stage2(a0,      a1,      As,            lo0, lo1);
    stage2(b0,      b1,      Bs,            lo0, lo1);
    stage2(a0 + 32, a1 + 32, As + SLOT,     lo0, lo1);
    stage2(b0 + 32, b1 + 32, Bs + SLOT,     lo0, lo1);
    stage2(a0 + 64, a1 + 64, As + 2 * SLOT, lo0, lo1);
    stage2(b0 + 64, b1 + 64, Bs + 2 * SLOT, lo0, lo1);
    tile_barrier<8>();

    for (int t = 0; t < T - 2; ++t)
        tile_body<true, true, 8, 8>(t, As, Bs, a0, a1, b0, b1, lo0, lo1, wm, wn, rk, acc);
    tile_body<true,  false, 8, 4>(T - 2, As, Bs, a0, a1, b0, b1, lo0, lo1, wm, wn, rk, acc);
    tile_body<false, false, 0, -1>(T - 1, As, Bs, a0, a1, b0, b1, lo0, lo1, wm, wn, rk, acc);
}

// ---------------------------------------------------------------------------
// W2 split-K: partial[slice][g][d] = sum_{f in slice*128..+128} WkT[g][f]WqT[d][f]
// Grid 128 = 16 (4x4 of 256^2) x 8 slices; T=2 K-tiles.
// ---------------------------------------------------------------------------
__global__ __launch_bounds__(512, 2) void w2split(
    const short* __restrict__ WkT, const short* __restrict__ WqT,
    float* __restrict__ Wpart)
{
    __shared__ short As[4 * SLOT], Bs[4 * SLOT];
    const int gt = blockIdx.x >> 3, slice = blockIdx.x & 7;
    const int gm = gt >> 2, gn = gt & 3;

    f32x4 acc[8][4];
#pragma unroll
    for (int m = 0; m < 8; ++m)
#pragma unroll
        for (int n = 0; n < 4; ++n) acc[m][n] = (f32x4){0.f, 0.f, 0.f, 0.f};

    gemm256(WkT + slice * 128, 1024, gm * 256,
            WqT + slice * 128, 1024, gn * 256, 2, As, Bs, acc);

    const int lane = threadIdx.x & 63;
    const int w    = threadIdx.x >> 6;
    const int wm   = (w >> 2) * 128;
    const int wn   = (w & 3) * 64;
    const int r    = lane & 15;
    const int qd   = lane >> 4;
    const int row_base = gm * 256 + wm + qd * 4;
    const int col_base = gn * 256 + wn + r;
    float* dst = Wpart + (size_t)slice * 1048576;
#pragma unroll
    for (int mf = 0; mf < 8; ++mf)
#pragma unroll
        for (int nf = 0; nf < 4; ++nf)
#pragma unroll
            for (int i = 0; i < 4; ++i)
                dst[(size_t)(row_base + mf * 16 + i) * 1024 + col_base + nf * 16] = acc[mf][nf][i];
}

// ---------------------------------------------------------------------------
// W2 reduce: W2Tb[g][d] = bf16(sum_slices).  Grid 1024 x 256, 4 elems/thread.
// ---------------------------------------------------------------------------
__global__ __launch_bounds__(256) void w2red(
    const float* __restrict__ Wpart, short* __restrict__ W2Tb)
{
    const int base = blockIdx.x * 1024 + threadIdx.x * 4;
    f32x4 s = (f32x4){0.f, 0.f, 0.f, 0.f};
#pragma unroll
    for (int sl = 0; sl < 8; ++sl) {
        f32x4 p = *(const f32x4*)(Wpart + (size_t)sl * 1048576 + base);
#pragma unroll
        for (int j = 0; j < 4; ++j) s[j] += p[j];
    }
    s16x4 o;
#pragma unroll
    for (int j = 0; j < 4; ++j) o[j] = bf16_bits(s[j]);
    *(s16x4*)(W2Tb + base) = o;
}

// ---------------------------------------------------------------------------
// proj: p0: Ybuf = Xbuf @ W2Tb^T (no bias); p1: vT = transpose(Xbuf @ Wvb^T + bv).
// Grid 512 = 64 mt x 4 nt x 2 p, XCD-chunked.
// ---------------------------------------------------------------------------
__global__ __launch_bounds__(512, 2) void proj(
    const short* __restrict__ Xbuf, const short* __restrict__ W2Tb,
    const short* __restrict__ Wvb, const float* __restrict__ bv,
    __hip_bfloat16* __restrict__ Ybuf, __hip_bfloat16* __restrict__ vT)
{
    __shared__ short As[4 * SLOT], Bs[4 * SLOT];
    const int bid  = blockIdx.x;
    const int id2  = (bid & 7) * 64 + (bid >> 3);   // bijective (512 % 8 == 0)
    const int mt   = id2 >> 3;
    const int rest = id2 & 7;
    const int nt   = rest & 3;
    const int p    = rest >> 2;

    const short* W = (p == 0) ? W2Tb : Wvb;

    f32x4 acc[8][4];
#pragma unroll
    for (int m = 0; m < 8; ++m)
#pragma unroll
        for (int n = 0; n < 4; ++n) acc[m][n] = (f32x4){0.f, 0.f, 0.f, 0.f};

    gemm256(Xbuf, DD, mt * 256, W, DD, nt * 256, DD / 64, As, Bs, acc);

    const int lane = threadIdx.x & 63;
    const int w    = threadIdx.x >> 6;
    const int wm   = (w >> 2) * 128;
    const int wn   = (w & 3) * 64;
    const int r    = lane & 15;
    const int qd   = lane >> 4;
    const int row_base = mt * 256 + wm + qd * 4;
    const int col_base = nt * 256 + wn + r;

    if (p == 0) {
#pragma unroll
        for (int nf = 0; nf < 4; ++nf) {
            const int col = col_base + nf * 16;
#pragma unroll
            for (int mf = 0; mf < 8; ++mf)
#pragma unroll
                for (int i = 0; i < 4; ++i)
                    Ybuf[(size_t)(row_base + mf * 16 + i) * FF + col] =
                        __float2bfloat16(acc[mf][nf][i]);
        }
    } else {
        // transposed V: lane's 4 regs = 4 consecutive t -> 8B packed store
#pragma unroll
        for (int mf = 0; mf < 8; ++mf) {
            const int rowg = row_base + mf * 16;
            const int b_   = rowg >> 11;
            const int t_   = rowg & 2047;
            __hip_bfloat16* vb = vT + (size_t)b_ * FF * TT;
#pragma unroll
            for (int nf = 0; nf < 4; ++nf) {
                const int col = col_base + nf * 16;
                const float bvv = bv[col];
                s16x4 pack;
#pragma unroll
                for (int i = 0; i < 4; ++i) pack[i] = bf16_bits(acc[mf][nf][i] + bvv);
                *(s16x4*)(vb + (size_t)col * TT + t_) = pack;
            }
        }
    }
}

// ---------------------------------------------------------------------------
// score: P[b][t][s] = exp2((y.x + w[s]) * scale*log2e) bf16, Z += rowsum.
// Grid 512 = 8 b x 8 tt x 8 st; XCD-chunked (one b per XCD).
// ---------------------------------------------------------------------------
__global__ __launch_bounds__(512, 2) void score256(
    const __hip_bfloat16* __restrict__ Ybuf, const short* __restrict__ Xbuf,
    const float* __restrict__ w, __hip_bfloat16* __restrict__ P,
    float* __restrict__ Z)
{
    __shared__ short As[4 * SLOT], Bs[4 * SLOT];
    const int bid = blockIdx.x;
    const int id2 = (bid & 7) * 64 + (bid >> 3);
    const int b   = id2 >> 6;
    const int tt  = (id2 >> 3) & 7;
    const int st  = id2 & 7;

    const short* yb = (const short*)Ybuf + (size_t)b * TT * FF;
    const short* xb = Xbuf + (size_t)b * TT * FF;

    f32x4 acc[8][4];
#pragma unroll
    for (int m = 0; m < 8; ++m)
#pragma unroll
        for (int n = 0; n < 4; ++n) acc[m][n] = (f32x4){0.f, 0.f, 0.f, 0.f};

    gemm256(yb, FF, tt * 256, xb, FF, st * 256, FF / 64, As, Bs, acc);

    const int lane = threadIdx.x & 63;
    const int wv   = threadIdx.x >> 6;
    const int wm   = (wv >> 2) * 128;
    const int wn   = (wv & 3) * 64;
    const int r    = lane & 15;
    const int qd   = lane >> 4;
    const int row_base = tt * 256 + wm + qd * 4;
    const int col_base = st * 256 + wn + r;

    __hip_bfloat16* Pb = P + (size_t)b * TT * TT;
    float* Zb = Z + b * TT;
    const float* wb = w + (size_t)b * TT;

    float rs[8][4];
#pragma unroll
    for (int mf = 0; mf < 8; ++mf)
#pragma unroll
        for (int i = 0; i < 4; ++i) rs[mf][i] = 0.f;

#pragma unroll
    for (int nf = 0; nf < 4; ++nf) {
        const int col = col_base + nf * 16;
        const float ws_ = wb[col];
#pragma unroll
        for (int mf = 0; mf < 8; ++mf)
#pragma unroll
            for (int i = 0; i < 4; ++i) {
                const float e = exp2f((acc[mf][nf][i] + ws_) * kScaleLog2e);
                const __hip_bfloat16 eb = __float2bfloat16(e);
                rs[mf][i] += __bfloat162float(eb);
                Pb[(size_t)(row_base + mf * 16 + i) * TT + col] = eb;
            }
    }
#pragma unroll
    for (int off = 1; off < 16; off <<= 1)
#pragma unroll
        for (int mf = 0; mf < 8; ++mf)
#pragma unroll
            for (int i = 0; i < 4; ++i) rs[mf][i] += __shfl_xor(rs[mf][i], off, 64);
    if (r == 0) {
#pragma unroll
        for (int mf = 0; mf < 8; ++mf)
#pragma unroll
            for (int i = 0; i < 4; ++i)
                atomicAdd(&Zb[row_base + mf * 16 + i], rs[mf][i]);
    }
}

// ---------------------------------------------------------------------------
// pv: out[b][t][f] = (P @ V)/Z via vT.  Grid 256 = 8 b x 8 tt x 4 ft.
// ---------------------------------------------------------------------------
__global__ __launch_bounds__(512, 2) void pv256(
    const __hip_bfloat16* __restrict__ P, const __hip_bfloat16* __restrict__ vT,
    const float* __restrict__ Z, float* __restrict__ out)
{
    __shared__ short As[4 * SLOT], Bs[4 * SLOT];
    const int bid = blockIdx.x;
    const int id2 = (bid & 7) * 32 + (bid >> 3);
    const int b   = id2 >> 5;
    const int tt  = (id2 >> 2) & 7;
    const int ft  = id2 & 3;

    const short* Pb = (const short*)P + (size_t)b * TT * TT;
    const short* vb = (const short*)vT + (size_t)b * FF * TT;

    f32x4 acc[8][4];
#pragma unroll
    for (int m = 0; m < 8; ++m)
#pragma unroll
        for (int n = 0; n < 4; ++n) acc[m][n] = (f32x4){0.f, 0.f, 0.f, 0.f};

    gemm256(Pb, TT, tt * 256, vb, TT, ft * 256, TT / 64, As, Bs, acc);

    const int lane = threadIdx.x & 63;
    const int w    = threadIdx.x >> 6;
    const int wm   = (w >> 2) * 128;
    const int wn   = (w & 3) * 64;
    const int r    = lane & 15;
    const int qd   = lane >> 4;
    const int row_base = tt * 256 + wm + qd * 4;
    const int col_base = ft * 256 + wn + r;

    const float* Zb = Z + b * TT;
    float* ob = out + (size_t)b * TT * FF;

#pragma unroll
    for (int mf = 0; mf < 8; ++mf) {
        float rz[4];
#pragma unroll
        for (int i = 0; i < 4; ++i) rz[i] = 1.0f / Zb[row_base + mf * 16 + i];
#pragma unroll
        for (int nf = 0; nf < 4; ++nf) {
            const int col = col_base + nf * 16;
#pragma unroll
            for (int i = 0; i < 4; ++i)
                ob[(size_t)(row_base + mf * 16 + i) * FF + col] = acc[mf][nf][i] * rz[i];
        }
    }
}

// ---------------------------------------------------------------------------
extern "C" void kernel_launch(void* const* d_in, const int* in_sizes, int n_in,
                              void* d_out, int out_size, void* d_ws, size_t ws_size,
                              hipStream_t stream) {
    const float* seq = (const float*)d_in[0];
    const float* Wq  = (const float*)d_in[1];
    const float* bq  = (const float*)d_in[2];
    const float* Wk  = (const float*)d_in[3];
    const float* bk  = (const float*)d_in[4];  (void)bk;  // cancels in softmax
    const float* Wv  = (const float*)d_in[5];
    const float* bv  = (const float*)d_in[6];
    float* out = (float*)d_out;
    char* ws = (char*)d_ws;

    // Workspace (167,837,696 B):
    //   Xbuf : 32 MiB @ 0          (bf16 x; score B-operand; persists)
    //   Ybuf : 32 MiB @ 32M        (bf16 y = x.W2)
    //   vT   : 32 MiB @ 64M
    //   P    : 64 MiB @ 96M        (pre-score aliases: WqT@+0 2M, WkT@+2M,
    //                               Wvb@+4M, W2Tb@+6M, Wpart@+8M 32M f32)
    //   Z    : 64 KiB @ 160M       (wv2 4 KiB aliases Z, dead before memset)
    //   w    : 64 KiB in d_out[0..64K) (dead before pv overwrites out)
    const size_t MB32 = 33554432;
    short* Xbuf = (short*)(ws);
    __hip_bfloat16* Ybuf = (__hip_bfloat16*)(ws + MB32);
    __hip_bfloat16* vT   = (__hip_bfloat16*)(ws + 2 * MB32);
    char*  Pr   = ws + 3 * MB32;
    __hip_bfloat16* P = (__hip_bfloat16*)Pr;
    short* WqT  = (short*)(Pr);
    short* WkT  = (short*)(Pr + 2097152);
    short* Wvb  = (short*)(Pr + 4194304);
    short* W2Tb = (short*)(Pr + 6291456);
    float* Wpart= (float*)(Pr + 8388608);
    float* Z    = (float*)(ws + 3 * MB32 + (size_t)67108864);
    float* wv2  = Z;                         // alias, dead before memset
    float* w    = (float*)d_out;             // dead before pv writes out

    cvt_all<<<9216, 256, 0, stream>>>(seq, Wq, Wk, Wv, Xbuf, Wvb, WqT, WkT);
    wv2k2<<<256, 256, 0, stream>>>(WkT, bq, wv2);
    wrow<<<4096, 256, 0, stream>>>(Xbuf, wv2, w);
    w2split<<<128, 512, 0, stream>>>(WkT, WqT, Wpart);
    w2red<<<1024, 256, 0, stream>>>(Wpart, W2Tb);
    proj<<<512, 512, 0, stream>>>(Xbuf, W2Tb, Wvb, bv, Ybuf, vT);
    hipMemsetAsync(Z, 0, (size_t)BB * TT * sizeof(float), stream);
    score256<<<BB * 64, 512, 0, stream>>>(Ybuf, Xbuf, w, P, Z);
    pv256<<<BB * 32, 512, 0, stream>>>(P, vT, Z, out);
}